// Round 16
// baseline (142.090 us; speedup 1.0000x reference)
//
#include <hip/hip_runtime.h>
#include <math.h>

// out[d] = s_ho*h_o[d] + s_h*h[d]; per-token scalars from 6 dot-reductions.
// The last untested config cell: FULL h+h_o preload (TPB=4 -> 32 VGPR of
// payload, fits under the 64-VGPR/8-waves-per-SIMD cliff) + single soft
// barrier (lgkmcnt-only, loads stay in flight) + redundant per-wave finalize
// (no second barrier, no s2 round-trip). Phase 2 has ZERO global loads: pure
// LDS-broadcast + fma + store.

constexpr int D    = 2048;
constexpr int RATE = 4;
constexpr float EPS = 1e-5f;
constexpr int TPB  = 4;    // tokens per block
constexpr int NT   = 512;  // threads; lane owns D/NT = 4 dims

__device__ __forceinline__ float fast_tanh(float x) {
    const float e = __expf(2.0f * x);
    return 1.0f - 2.0f / (e + 1.0f);
}

template<int CTRL>
__device__ __forceinline__ float dpp_add(float x) {
    int m = __builtin_amdgcn_update_dpp(0, __float_as_int(x), CTRL, 0xf, 0xf, true);
    return x + __int_as_float(m);
}

// After this, lane 63 holds the 64-lane sum.
__device__ __forceinline__ float wave_sum_lane63(float x) {
    x = dpp_add<0x111>(x);  // row_shr:1
    x = dpp_add<0x112>(x);  // row_shr:2
    x = dpp_add<0x114>(x);  // row_shr:4
    x = dpp_add<0x118>(x);  // row_shr:8
    x = dpp_add<0x142>(x);  // row_bcast:15
    x = dpp_add<0x143>(x);  // row_bcast:31
    return x;
}

// LDS-only block sync: no vmcnt(0) drain, outstanding global loads survive.
__device__ __forceinline__ void lds_barrier() {
    asm volatile("s_waitcnt lgkmcnt(0)" ::: "memory");
    __builtin_amdgcn_s_barrier();
    __builtin_amdgcn_sched_barrier(0);
}

__global__ __launch_bounds__(NT, 8) void hyperconn_kernel(
    const float* __restrict__ h,
    const float* __restrict__ h_o,
    const float* __restrict__ sa,    // [4][5]
    const float* __restrict__ sb,    // [4]
    const float* __restrict__ fa,    // [2048][5]
    const float* __restrict__ a_sc,  // [1]
    const float* __restrict__ fb,    // [2048]
    const float* __restrict__ b_sc,  // [1]
    const float* __restrict__ w,     // [2048]
    float* __restrict__ out)
{
    const int tid  = threadIdx.x;          // 0..511
    const int d0   = tid * 4;
    const int wave = tid >> 6;             // 0..7
    const int lane = tid & 63;
    const size_t t0 = (size_t)blockIdx.x * TPB;

    // ---- the block's ENTIRE HBM read stream, issued first: 4x h, 4x h_o
    float4 hA[TPB], oA[TPB];
    #pragma unroll
    for (int i = 0; i < TPB; ++i)
        hA[i] = *reinterpret_cast<const float4*>(h + (t0 + i) * D + d0);
    #pragma unroll
    for (int i = 0; i < TPB; ++i)
        oA[i] = *reinterpret_cast<const float4*>(h_o + (t0 + i) * D + d0);

    // ---- prefolded tables: wfa_c[j] = w*fa[.][c+1], wfb[j] = w*fb (20 VGPR)
    float fav[16], fbv[4];
    {
        const float4 wq = *reinterpret_cast<const float4*>(w + d0);
        const float ww[4] = {wq.x, wq.y, wq.z, wq.w};
        float tmp[20];
        #pragma unroll
        for (int q = 0; q < 5; ++q) {
            float4 t = *reinterpret_cast<const float4*>(fa + (size_t)d0 * 5 + q * 4);
            tmp[q*4+0]=t.x; tmp[q*4+1]=t.y; tmp[q*4+2]=t.z; tmp[q*4+3]=t.w;
        }
        #pragma unroll
        for (int j = 0; j < 4; ++j)
            #pragma unroll
            for (int c = 0; c < 4; ++c)
                fav[j*4+c] = ww[j] * tmp[j*5 + 1 + c];
        const float4 fq = *reinterpret_cast<const float4*>(fb + d0);
        fbv[0] = ww[0]*fq.x; fbv[1] = ww[1]*fq.y;
        fbv[2] = ww[2]*fq.z; fbv[3] = ww[3]*fq.w;
    }

    const float a4 = a_sc[0] * (float)RATE;
    const float b4 = b_sc[0] * (float)RATE;
    float cs = 0.f;
    #pragma unroll
    for (int r = 0; r < RATE; ++r)
        #pragma unroll
        for (int c = 1; c <= RATE; ++c)
            cs += sa[r * (RATE + 1) + c];
    const float sbsum = sb[0] + sb[1] + sb[2] + sb[3];

    __shared__ float red[TPB][48];   // [token][wave*6+k]

    // ---- phase 1: per-token partials + DPP reduce (no syncs inside)
    #pragma unroll
    for (int i = 0; i < TPB; ++i) {
        const float hv[4] = {hA[i].x, hA[i].y, hA[i].z, hA[i].w};
        float acc[6] = {0.f, 0.f, 0.f, 0.f, 0.f, 0.f};
        #pragma unroll
        for (int j = 0; j < 4; ++j) {
            const float x = hv[j];
            acc[0] = fmaf(x, x,          acc[0]);
            acc[1] = fmaf(x, fav[j*4+0], acc[1]);
            acc[2] = fmaf(x, fav[j*4+1], acc[2]);
            acc[3] = fmaf(x, fav[j*4+2], acc[3]);
            acc[4] = fmaf(x, fav[j*4+3], acc[4]);
            acc[5] = fmaf(x, fbv[j],     acc[5]);
        }
        #pragma unroll
        for (int k = 0; k < 6; ++k) acc[k] = wave_sum_lane63(acc[k]);
        if (lane == 63) {
            #pragma unroll
            for (int k = 0; k < 6; ++k) red[i][wave * 6 + k] = acc[k];
        }
    }

    lds_barrier();   // the ONE barrier; h_o loads remain in flight

    // ---- phase 2: redundant per-wave finalize (uniform LDS broadcasts)
    //      then fma + store; zero global loads here
    #pragma unroll
    for (int i = 0; i < TPB; ++i) {
        float tot[6] = {0.f, 0.f, 0.f, 0.f, 0.f, 0.f};
        #pragma unroll
        for (int v = 0; v < 8; ++v)
            #pragma unroll
            for (int k = 0; k < 6; ++k)
                tot[k] += red[i][v * 6 + k];
        const float rms  = rsqrtf(tot[0] * (1.0f / (float)D) + EPS);
        const float s_h  = a4 * (fast_tanh(tot[1] * rms) + fast_tanh(tot[2] * rms) +
                                 fast_tanh(tot[3] * rms) + fast_tanh(tot[4] * rms)) + cs;
        const float s_ho = b4 * fast_tanh(tot[5] * rms) + sbsum;

        const size_t base = (t0 + i) * D + d0;
        float4 r;
        r.x = fmaf(s_ho, oA[i].x, s_h * hA[i].x);
        r.y = fmaf(s_ho, oA[i].y, s_h * hA[i].y);
        r.z = fmaf(s_ho, oA[i].z, s_h * hA[i].z);
        r.w = fmaf(s_ho, oA[i].w, s_h * hA[i].w);
        *reinterpret_cast<float4*>(out + base) = r;
    }
}

extern "C" void kernel_launch(void* const* d_in, const int* in_sizes, int n_in,
                              void* d_out, int out_size, void* d_ws, size_t ws_size,
                              hipStream_t stream) {
    const float* h    = (const float*)d_in[0];
    const float* h_o  = (const float*)d_in[1];
    const float* sa   = (const float*)d_in[2];
    const float* sb   = (const float*)d_in[3];
    const float* fa   = (const float*)d_in[4];
    const float* a_sc = (const float*)d_in[5];
    const float* fb   = (const float*)d_in[6];
    const float* b_sc = (const float*)d_in[7];
    const float* w    = (const float*)d_in[8];
    float* out = (float*)d_out;

    const int ntok   = in_sizes[0] / D;       // B*L = 16384
    const int blocks = ntok / TPB;            // 4096
    hyperconn_kernel<<<blocks, NT, 0, stream>>>(h, h_o, sa, sb, fa, a_sc, fb, b_sc, w, out);
}

// Round 17
// 76.924 us; speedup vs baseline: 1.8471x; 1.8471x over previous
//
#include <hip/hip_runtime.h>
#include <math.h>

// out[d] = s_ho*h_o[d] + s_h*h[d]; per-token scalars from 6 dot-reductions.
// BEST CONFIG (R15, 77.6us = 5.2 TB/s logical): TPB=4, 512 threads, VGPR<=64
// via __launch_bounds__(512,8) -> 8 waves/SIMD resident; h in registers
// across the soft (lgkmcnt-only) barriers; h_o loaded in phase 2 (holding it
// across the barrier needs >64 VGPR and spills - R16 proved: WRITE_SIZE
// 131->360MB scratch traffic, 142us). w prefolded into fa/fb tables.
// Experiment matrix closed: full-preload@4waves=79.7, minimal@8waves=77.6,
// full-preload@8waves=spill, wave-per-token=VGPR blowup. This is the corner.

constexpr int D    = 2048;
constexpr int RATE = 4;
constexpr float EPS = 1e-5f;
constexpr int TPB  = 4;    // tokens per block
constexpr int NT   = 512;  // threads; lane owns D/NT = 4 dims

__device__ __forceinline__ float fast_tanh(float x) {
    const float e = __expf(2.0f * x);
    return 1.0f - 2.0f / (e + 1.0f);
}

template<int CTRL>
__device__ __forceinline__ float dpp_add(float x) {
    int m = __builtin_amdgcn_update_dpp(0, __float_as_int(x), CTRL, 0xf, 0xf, true);
    return x + __int_as_float(m);
}

// After this, lane 63 holds the 64-lane sum.
__device__ __forceinline__ float wave_sum_lane63(float x) {
    x = dpp_add<0x111>(x);  // row_shr:1
    x = dpp_add<0x112>(x);  // row_shr:2
    x = dpp_add<0x114>(x);  // row_shr:4
    x = dpp_add<0x118>(x);  // row_shr:8
    x = dpp_add<0x142>(x);  // row_bcast:15
    x = dpp_add<0x143>(x);  // row_bcast:31
    return x;
}

// LDS-only block sync: no vmcnt(0) drain, outstanding global loads survive.
__device__ __forceinline__ void lds_barrier() {
    asm volatile("s_waitcnt lgkmcnt(0)" ::: "memory");
    __builtin_amdgcn_s_barrier();
    __builtin_amdgcn_sched_barrier(0);
}

__global__ __launch_bounds__(NT, 8) void hyperconn_kernel(
    const float* __restrict__ h,
    const float* __restrict__ h_o,
    const float* __restrict__ sa,    // [4][5]
    const float* __restrict__ sb,    // [4]
    const float* __restrict__ fa,    // [2048][5]
    const float* __restrict__ a_sc,  // [1]
    const float* __restrict__ fb,    // [2048]
    const float* __restrict__ b_sc,  // [1]
    const float* __restrict__ w,     // [2048]
    float* __restrict__ out)
{
    const int tid  = threadIdx.x;          // 0..511
    const int d0   = tid * 4;
    const int wave = tid >> 6;             // 0..7
    const int lane = tid & 63;
    const size_t t0 = (size_t)blockIdx.x * TPB;

    // ---- h for the block's 4 tokens -> registers (16 VGPR), issued first
    float4 hA[TPB];
    #pragma unroll
    for (int i = 0; i < TPB; ++i)
        hA[i] = *reinterpret_cast<const float4*>(h + (t0 + i) * D + d0);

    // ---- prefolded tables: wfa_c[j] = w*fa[.][c+1], wfb[j] = w*fb  (20 VGPR)
    float fav[16], fbv[4];
    {
        const float4 wq = *reinterpret_cast<const float4*>(w + d0);
        const float ww[4] = {wq.x, wq.y, wq.z, wq.w};
        float tmp[20];
        #pragma unroll
        for (int q = 0; q < 5; ++q) {
            float4 t = *reinterpret_cast<const float4*>(fa + (size_t)d0 * 5 + q * 4);
            tmp[q*4+0]=t.x; tmp[q*4+1]=t.y; tmp[q*4+2]=t.z; tmp[q*4+3]=t.w;
        }
        #pragma unroll
        for (int j = 0; j < 4; ++j)
            #pragma unroll
            for (int c = 0; c < 4; ++c)
                fav[j*4+c] = ww[j] * tmp[j*5 + 1 + c];
        const float4 fq = *reinterpret_cast<const float4*>(fb + d0);
        fbv[0] = ww[0]*fq.x; fbv[1] = ww[1]*fq.y;
        fbv[2] = ww[2]*fq.z; fbv[3] = ww[3]*fq.w;
    }

    const float a4 = a_sc[0] * (float)RATE;
    const float b4 = b_sc[0] * (float)RATE;
    float cs = 0.f;
    #pragma unroll
    for (int r = 0; r < RATE; ++r)
        #pragma unroll
        for (int c = 1; c <= RATE; ++c)
            cs += sa[r * (RATE + 1) + c];
    const float sbsum = sb[0] + sb[1] + sb[2] + sb[3];

    __shared__ float  red[TPB][48];   // [token][wave*6+k]
    __shared__ float2 s2[TPB];        // (s_h, s_ho) per token

    // ---- phase 1: per-token partials + DPP reduce (no syncs inside)
    #pragma unroll
    for (int i = 0; i < TPB; ++i) {
        const float hv[4] = {hA[i].x, hA[i].y, hA[i].z, hA[i].w};
        float acc[6] = {0.f, 0.f, 0.f, 0.f, 0.f, 0.f};
        #pragma unroll
        for (int j = 0; j < 4; ++j) {
            const float x = hv[j];
            acc[0] = fmaf(x, x,          acc[0]);
            acc[1] = fmaf(x, fav[j*4+0], acc[1]);
            acc[2] = fmaf(x, fav[j*4+1], acc[2]);
            acc[3] = fmaf(x, fav[j*4+2], acc[3]);
            acc[4] = fmaf(x, fav[j*4+3], acc[4]);
            acc[5] = fmaf(x, fbv[j],     acc[5]);
        }
        #pragma unroll
        for (int k = 0; k < 6; ++k) acc[k] = wave_sum_lane63(acc[k]);
        if (lane == 63) {
            #pragma unroll
            for (int k = 0; k < 6; ++k) red[i][wave * 6 + k] = acc[k];
        }
    }

    lds_barrier();

    // ---- finalize: wave i (i<TPB) handles token i
    if (wave < TPB) {
        const int i = wave;
        float tot[6] = {0.f, 0.f, 0.f, 0.f, 0.f, 0.f};
        #pragma unroll
        for (int v = 0; v < 8; ++v)
            #pragma unroll
            for (int k = 0; k < 6; ++k)
                tot[k] += red[i][v * 6 + k];
        const float rms  = rsqrtf(tot[0] * (1.0f / (float)D) + EPS);
        const float s_h  = a4 * (fast_tanh(tot[1] * rms) + fast_tanh(tot[2] * rms) +
                                 fast_tanh(tot[3] * rms) + fast_tanh(tot[4] * rms)) + cs;
        const float s_ho = b4 * fast_tanh(tot[5] * rms) + sbsum;
        if (lane == 0) s2[i] = make_float2(s_h, s_ho);
    }

    lds_barrier();

    // ---- phase 2: h_o stream + fma + store; h already in registers
    #pragma unroll
    for (int i = 0; i < TPB; ++i) {
        const float2 s = s2[i];
        const size_t base = (t0 + i) * D + d0;
        const float4 oq = *reinterpret_cast<const float4*>(h_o + base);
        float4 r;
        r.x = fmaf(s.y, oq.x, s.x * hA[i].x);
        r.y = fmaf(s.y, oq.y, s.x * hA[i].y);
        r.z = fmaf(s.y, oq.z, s.x * hA[i].z);
        r.w = fmaf(s.y, oq.w, s.x * hA[i].w);
        *reinterpret_cast<float4*>(out + base) = r;
    }
}

extern "C" void kernel_launch(void* const* d_in, const int* in_sizes, int n_in,
                              void* d_out, int out_size, void* d_ws, size_t ws_size,
                              hipStream_t stream) {
    const float* h    = (const float*)d_in[0];
    const float* h_o  = (const float*)d_in[1];
    const float* sa   = (const float*)d_in[2];
    const float* sb   = (const float*)d_in[3];
    const float* fa   = (const float*)d_in[4];
    const float* a_sc = (const float*)d_in[5];
    const float* fb   = (const float*)d_in[6];
    const float* b_sc = (const float*)d_in[7];
    const float* w    = (const float*)d_in[8];
    float* out = (float*)d_out;

    const int ntok   = in_sizes[0] / D;       // B*L = 16384
    const int blocks = ntok / TPB;            // 4096
    hyperconn_kernel<<<blocks, NT, 0, stream>>>(h, h_o, sa, sb, fa, a_sc, fb, b_sc, w, out);
}